// Round 1
// baseline (567.078 us; speedup 1.0000x reference)
//
#include <hip/hip_runtime.h>
#include <hip/hip_bf16.h>

#define NEG_SLOPE 0.2f

// ---------------------------------------------------------------------------
// Tiled f32 GEMM: D[V,128] = act(A[V,128] @ W[128,128] + bias), optional lrelu
// BM=64, BN=128 (full), BK=32. 256 threads, each computes 4 rows x 8 cols.
// ---------------------------------------------------------------------------
__global__ __launch_bounds__(256) void gemm128(const float* __restrict__ A,
                                               const float* __restrict__ W,
                                               const float* __restrict__ bias,
                                               float* __restrict__ D,
                                               int V, int lrelu)
{
    __shared__ float As[32][65];    // transposed [k][row], padded
    __shared__ float Bs[32][128];   // [k][col]
    const int tid = threadIdx.x;
    const int tx = tid & 15;        // col group
    const int ty = tid >> 4;        // row group
    const int row0 = blockIdx.x * 64;

    float acc[4][8];
#pragma unroll
    for (int i = 0; i < 4; ++i)
#pragma unroll
        for (int j = 0; j < 8; ++j) acc[i][j] = 0.f;

    for (int k0 = 0; k0 < 128; k0 += 32) {
        // stage A tile (64 rows x 32 k), transposed into LDS
        {
            const int c = (tid & 7) * 4;
#pragma unroll
            for (int p = 0; p < 2; ++p) {
                const int r = (tid >> 3) + 32 * p;
                const int gr = row0 + r;
                float4 a = make_float4(0.f, 0.f, 0.f, 0.f);
                if (gr < V) a = *(const float4*)(A + (size_t)gr * 128 + k0 + c);
                As[c + 0][r] = a.x; As[c + 1][r] = a.y;
                As[c + 2][r] = a.z; As[c + 3][r] = a.w;
            }
        }
        // stage B tile (32 k x 128 cols)
        {
            const int r = tid >> 5;
            const int c = (tid & 31) * 4;
#pragma unroll
            for (int p = 0; p < 4; ++p) {
                float4 b = *(const float4*)(W + (size_t)(k0 + r + 8 * p) * 128 + c);
                *(float4*)&Bs[r + 8 * p][c] = b;
            }
        }
        __syncthreads();
#pragma unroll
        for (int kk = 0; kk < 32; ++kk) {
            float a[4];
#pragma unroll
            for (int i = 0; i < 4; ++i) a[i] = As[kk][ty * 4 + i];
            const float4 b0 = *(const float4*)&Bs[kk][tx * 8];
            const float4 b1 = *(const float4*)&Bs[kk][tx * 8 + 4];
            const float b[8] = {b0.x, b0.y, b0.z, b0.w, b1.x, b1.y, b1.z, b1.w};
#pragma unroll
            for (int i = 0; i < 4; ++i)
#pragma unroll
                for (int j = 0; j < 8; ++j) acc[i][j] += a[i] * b[j];
        }
        __syncthreads();
    }

#pragma unroll
    for (int i = 0; i < 4; ++i) {
        const int gr = row0 + ty * 4 + i;
        if (gr >= V) continue;
#pragma unroll
        for (int j = 0; j < 8; j += 4) {
            float4 o;
            float* op = &o.x;
#pragma unroll
            for (int jj = 0; jj < 4; ++jj) {
                const int c = tx * 8 + j + jj;
                float x = acc[i][j + jj] + bias[c];
                if (lrelu) x = (x > 0.f) ? x : NEG_SLOPE * x;
                op[jj] = x;
            }
            *(float4*)(D + (size_t)gr * 128 + tx * 8 + j) = o;
        }
    }
}

// ---------------------------------------------------------------------------
// Per-(edge,head) attention logit: exp(dot(Q[src],K[tgt])/sqrt(32)+bias)
// Accumulates softmax denominator per (tgt,head); counts edges per tgt.
// ---------------------------------------------------------------------------
__global__ __launch_bounds__(256) void edge_logits(
    const int* __restrict__ src, const int* __restrict__ tgt,
    const float* __restrict__ ew, const float* __restrict__ Q,
    const float* __restrict__ K, const float* __restrict__ Wei,
    const float* __restrict__ bei, float* __restrict__ attn,
    float* __restrict__ deg, int* __restrict__ cnt, long long EH)
{
    const long long gid = (long long)blockIdx.x * blockDim.x + threadIdx.x;
    if (gid >= EH) return;
    const int e  = (int)(gid >> 2);
    const int hh = (int)(gid & 3);
    const int s = src[e], t = tgt[e];
    const float4* qp = (const float4*)(Q + (size_t)s * 128 + hh * 32);
    const float4* kp = (const float4*)(K + (size_t)t * 128 + hh * 32);
    float dot = 0.f;
#pragma unroll
    for (int i = 0; i < 8; ++i) {
        const float4 q = qp[i], k = kp[i];
        dot += q.x * k.x + q.y * k.y + q.z * k.z + q.w * k.w;
    }
    const float w = ew[e];
    float b = w * Wei[hh] + bei[hh];
    b = (b > 0.f) ? b : NEG_SLOPE * b;
    const float ex = __expf(dot * 0.17677669529663687f + b);  // 1/sqrt(32)
    attn[(size_t)e * 4 + hh] = ex;
    atomicAdd(deg + (size_t)t * 4 + hh, ex);
    if (hh == 0) atomicAdd(cnt + t, 1);
}

// ---------------------------------------------------------------------------
// CSR build: block-wise exclusive scan of per-node counts
// ---------------------------------------------------------------------------
__global__ __launch_bounds__(256) void scan1(const int* __restrict__ cnt,
                                             int* __restrict__ offs,
                                             int* __restrict__ bsums, int V)
{
    __shared__ int sh[256];
    const int t = threadIdx.x;
    const int base = blockIdx.x * 1024;
    int v[4];
    int s = 0;
#pragma unroll
    for (int i = 0; i < 4; ++i) {
        const int idx = base + t * 4 + i;
        v[i] = (idx < V) ? cnt[idx] : 0;
        s += v[i];
    }
    sh[t] = s;
    __syncthreads();
    for (int off = 1; off < 256; off <<= 1) {
        const int x = (t >= off) ? sh[t - off] : 0;
        __syncthreads();
        sh[t] += x;
        __syncthreads();
    }
    int run = (t > 0) ? sh[t - 1] : 0;
#pragma unroll
    for (int i = 0; i < 4; ++i) {
        const int idx = base + t * 4 + i;
        if (idx < V) offs[idx] = run;
        run += v[i];
    }
    if (t == 255) bsums[blockIdx.x] = sh[255];
}

__global__ void scan2(int* __restrict__ bsums, int nb)
{
    if (threadIdx.x == 0 && blockIdx.x == 0) {
        int run = 0;
        for (int i = 0; i < nb; ++i) { const int x = bsums[i]; bsums[i] = run; run += x; }
    }
}

__global__ __launch_bounds__(256) void scan3(int* __restrict__ offs,
                                             const int* __restrict__ bsums,
                                             int* __restrict__ fill, int V)
{
    const int v = blockIdx.x * blockDim.x + threadIdx.x;
    if (v >= V) return;
    const int o = offs[v] + bsums[v >> 10];
    offs[v] = o;
    fill[v] = o;
}

__global__ __launch_bounds__(256) void scatter_edges(const int* __restrict__ tgt,
                                                     int* __restrict__ fill,
                                                     int* __restrict__ eids, int E)
{
    const int e = blockIdx.x * blockDim.x + threadIdx.x;
    if (e >= E) return;
    const int pos = atomicAdd(fill + tgt[e], 1);
    eids[pos] = e;
}

// ---------------------------------------------------------------------------
// Per-node aggregation: accum[v,d] = sum_e attn[e,h]/deg[v,h]*ew[e]*Vv[src,d]
// 256 threads = 2 nodes x 128 dims. Coalesced Vv row reads, no atomics.
// ---------------------------------------------------------------------------
__global__ __launch_bounds__(256) void gather_agg(
    const float* __restrict__ Vv, const float* __restrict__ attn,
    const float* __restrict__ deg, const float* __restrict__ ew,
    const int* __restrict__ src, const int* __restrict__ offs,
    const int* __restrict__ fill, const int* __restrict__ eids,
    float* __restrict__ accum, int V)
{
    const int node = blockIdx.x * 2 + (threadIdx.x >> 7);
    if (node >= V) return;
    const int d  = threadIdx.x & 127;
    const int hh = d >> 5;
    const int start = offs[node];
    const int end   = fill[node];   // == offs[node] + count after scatter
    const float inv = 1.0f / (deg[(size_t)node * 4 + hh] + 1e-16f);
    float acc = 0.f;
    for (int p = start; p < end; ++p) {
        const int e = eids[p];
        const int s = src[e];
        const float c = attn[(size_t)e * 4 + hh] * ew[e] * inv;
        acc += c * Vv[(size_t)s * 128 + d];
    }
    accum[(size_t)node * 128 + d] = acc;
}

// ---------------------------------------------------------------------------
extern "C" void kernel_launch(void* const* d_in, const int* in_sizes, int n_in,
                              void* d_out, int out_size, void* d_ws, size_t ws_size,
                              hipStream_t stream)
{
    const float* h   = (const float*)d_in[0];
    const int*   ei  = (const int*)  d_in[1];
    const float* ew  = (const float*)d_in[2];
    const float* Wq  = (const float*)d_in[3];
    const float* bq  = (const float*)d_in[4];
    const float* Wk  = (const float*)d_in[5];
    const float* bk  = (const float*)d_in[6];
    const float* Wv  = (const float*)d_in[7];
    const float* bv  = (const float*)d_in[8];
    const float* Wo  = (const float*)d_in[9];
    const float* bo  = (const float*)d_in[10];
    const float* Wei = (const float*)d_in[11];
    const float* bei = (const float*)d_in[12];

    const int V = in_sizes[0] / 128;
    const int E = in_sizes[2];
    const int* src = ei;
    const int* tgt = ei + E;

    // workspace layout (floats then ints)
    float* Q     = (float*)d_ws;
    float* Km    = Q  + (size_t)V * 128;
    float* Vm    = Km + (size_t)V * 128;
    float* attn  = Vm + (size_t)V * 128;
    float* deg   = attn + (size_t)E * 4;
    float* accum = deg + (size_t)V * 4;
    int*   cnt   = (int*)(accum + (size_t)V * 128);
    int*   offs  = cnt  + V;
    int*   fill  = offs + V + 1;
    int*   eids  = fill + V;
    int*   bsums = eids + E;

    // zero deg + cnt every call (harness does not re-poison between replays)
    hipMemsetAsync(deg, 0, (size_t)V * 4 * sizeof(float), stream);
    hipMemsetAsync(cnt, 0, (size_t)V * sizeof(int), stream);

    const int gemmGrid = (V + 63) / 64;
    gemm128<<<gemmGrid, 256, 0, stream>>>(h, Wq, bq, Q,  V, 0);
    gemm128<<<gemmGrid, 256, 0, stream>>>(h, Wk, bk, Km, V, 0);
    gemm128<<<gemmGrid, 256, 0, stream>>>(h, Wv, bv, Vm, V, 0);

    const long long EH = (long long)E * 4;
    edge_logits<<<(int)((EH + 255) / 256), 256, 0, stream>>>(
        src, tgt, ew, Q, Km, Wei, bei, attn, deg, cnt, EH);

    const int nb = (V + 1023) / 1024;
    scan1<<<nb, 256, 0, stream>>>(cnt, offs, bsums, V);
    scan2<<<1, 64, 0, stream>>>(bsums, nb);
    scan3<<<(V + 255) / 256, 256, 0, stream>>>(offs, bsums, fill, V);
    scatter_edges<<<(E + 255) / 256, 256, 0, stream>>>(tgt, fill, eids, E);

    gather_agg<<<(V + 1) / 2, 256, 0, stream>>>(
        Vm, attn, deg, ew, src, offs, fill, eids, accum, V);

    gemm128<<<gemmGrid, 256, 0, stream>>>(accum, Wo, bo, (float*)d_out, V, 1);
}

// Round 2
// 393.711 us; speedup vs baseline: 1.4403x; 1.4403x over previous
//
#include <hip/hip_runtime.h>
#include <hip/hip_bf16.h>

#define NEG_SLOPE 0.2f

// ---------------------------------------------------------------------------
// Tiled f32 GEMM: D[V,128] = act(A[V,128] @ W[128,128] + bias), optional lrelu
// BM=64, BN=128 (full), BK=32. 256 threads, each computes 4 rows x 8 cols.
// ---------------------------------------------------------------------------
__global__ __launch_bounds__(256) void gemm128(const float* __restrict__ A,
                                               const float* __restrict__ W,
                                               const float* __restrict__ bias,
                                               float* __restrict__ D,
                                               int V, int lrelu)
{
    __shared__ float As[32][65];    // transposed [k][row], padded
    __shared__ float Bs[32][128];   // [k][col]
    const int tid = threadIdx.x;
    const int tx = tid & 15;        // col group
    const int ty = tid >> 4;        // row group
    const int row0 = blockIdx.x * 64;

    float acc[4][8];
#pragma unroll
    for (int i = 0; i < 4; ++i)
#pragma unroll
        for (int j = 0; j < 8; ++j) acc[i][j] = 0.f;

    for (int k0 = 0; k0 < 128; k0 += 32) {
        {
            const int c = (tid & 7) * 4;
#pragma unroll
            for (int p = 0; p < 2; ++p) {
                const int r = (tid >> 3) + 32 * p;
                const int gr = row0 + r;
                float4 a = make_float4(0.f, 0.f, 0.f, 0.f);
                if (gr < V) a = *(const float4*)(A + (size_t)gr * 128 + k0 + c);
                As[c + 0][r] = a.x; As[c + 1][r] = a.y;
                As[c + 2][r] = a.z; As[c + 3][r] = a.w;
            }
        }
        {
            const int r = tid >> 5;
            const int c = (tid & 31) * 4;
#pragma unroll
            for (int p = 0; p < 4; ++p) {
                float4 b = *(const float4*)(W + (size_t)(k0 + r + 8 * p) * 128 + c);
                *(float4*)&Bs[r + 8 * p][c] = b;
            }
        }
        __syncthreads();
#pragma unroll 8
        for (int kk = 0; kk < 32; ++kk) {
            float a[4];
#pragma unroll
            for (int i = 0; i < 4; ++i) a[i] = As[kk][ty * 4 + i];
            const float4 b0 = *(const float4*)&Bs[kk][tx * 8];
            const float4 b1 = *(const float4*)&Bs[kk][tx * 8 + 4];
            const float b[8] = {b0.x, b0.y, b0.z, b0.w, b1.x, b1.y, b1.z, b1.w};
#pragma unroll
            for (int i = 0; i < 4; ++i)
#pragma unroll
                for (int j = 0; j < 8; ++j) acc[i][j] += a[i] * b[j];
        }
        __syncthreads();
    }

#pragma unroll
    for (int i = 0; i < 4; ++i) {
        const int gr = row0 + ty * 4 + i;
        if (gr >= V) continue;
#pragma unroll
        for (int j = 0; j < 8; j += 4) {
            float4 o;
            float* op = &o.x;
#pragma unroll
            for (int jj = 0; jj < 4; ++jj) {
                const int c = tx * 8 + j + jj;
                float x = acc[i][j + jj] + bias[c];
                if (lrelu) x = (x > 0.f) ? x : NEG_SLOPE * x;
                op[jj] = x;
            }
            *(float4*)(D + (size_t)gr * 128 + tx * 8 + j) = o;
        }
    }
}

// ---------------------------------------------------------------------------
// Fused Q/K/V projection: three GEMMs sharing the A-tile staging.
// ---------------------------------------------------------------------------
__global__ __launch_bounds__(256) void gemm_qkv(
    const float* __restrict__ A,
    const float* __restrict__ W0, const float* __restrict__ W1, const float* __restrict__ W2,
    const float* __restrict__ b0, const float* __restrict__ b1, const float* __restrict__ b2,
    float* __restrict__ D0, float* __restrict__ D1, float* __restrict__ D2, int V)
{
    __shared__ float As[32][65];
    __shared__ float Bs[3][32][128];
    const int tid = threadIdx.x;
    const int tx = tid & 15;
    const int ty = tid >> 4;
    const int row0 = blockIdx.x * 64;
    const float* Ws[3] = {W0, W1, W2};
    const float* bs[3] = {b0, b1, b2};
    float* Ds[3] = {D0, D1, D2};

    float acc[3][4][8];
#pragma unroll
    for (int m = 0; m < 3; ++m)
#pragma unroll
        for (int i = 0; i < 4; ++i)
#pragma unroll
            for (int j = 0; j < 8; ++j) acc[m][i][j] = 0.f;

    for (int k0 = 0; k0 < 128; k0 += 32) {
        {
            const int c = (tid & 7) * 4;
#pragma unroll
            for (int p = 0; p < 2; ++p) {
                const int r = (tid >> 3) + 32 * p;
                const int gr = row0 + r;
                float4 a = make_float4(0.f, 0.f, 0.f, 0.f);
                if (gr < V) a = *(const float4*)(A + (size_t)gr * 128 + k0 + c);
                As[c + 0][r] = a.x; As[c + 1][r] = a.y;
                As[c + 2][r] = a.z; As[c + 3][r] = a.w;
            }
        }
        {
            const int r = tid >> 5;
            const int c = (tid & 31) * 4;
#pragma unroll
            for (int m = 0; m < 3; ++m)
#pragma unroll
                for (int p = 0; p < 4; ++p) {
                    float4 b = *(const float4*)(Ws[m] + (size_t)(k0 + r + 8 * p) * 128 + c);
                    *(float4*)&Bs[m][r + 8 * p][c] = b;
                }
        }
        __syncthreads();
#pragma unroll 4
        for (int kk = 0; kk < 32; ++kk) {
            float a[4];
#pragma unroll
            for (int i = 0; i < 4; ++i) a[i] = As[kk][ty * 4 + i];
#pragma unroll
            for (int m = 0; m < 3; ++m) {
                const float4 q0 = *(const float4*)&Bs[m][kk][tx * 8];
                const float4 q1 = *(const float4*)&Bs[m][kk][tx * 8 + 4];
                const float b[8] = {q0.x, q0.y, q0.z, q0.w, q1.x, q1.y, q1.z, q1.w};
#pragma unroll
                for (int i = 0; i < 4; ++i)
#pragma unroll
                    for (int j = 0; j < 8; ++j) acc[m][i][j] += a[i] * b[j];
            }
        }
        __syncthreads();
    }

#pragma unroll
    for (int m = 0; m < 3; ++m)
#pragma unroll
        for (int i = 0; i < 4; ++i) {
            const int gr = row0 + ty * 4 + i;
            if (gr >= V) continue;
#pragma unroll
            for (int j = 0; j < 8; j += 4) {
                float4 o;
                float* op = &o.x;
#pragma unroll
                for (int jj = 0; jj < 4; ++jj)
                    op[jj] = acc[m][i][j + jj] + bs[m][tx * 8 + j + jj];
                *(float4*)(Ds[m] + (size_t)gr * 128 + tx * 8 + j) = o;
            }
        }
}

// ---------------------------------------------------------------------------
// Per-(edge,head) attention logit: exp(dot(Q[src],K[tgt])/sqrt(32)+bias)
// ---------------------------------------------------------------------------
__global__ __launch_bounds__(256) void edge_logits(
    const int* __restrict__ src, const int* __restrict__ tgt,
    const float* __restrict__ ew, const float* __restrict__ Q,
    const float* __restrict__ K, const float* __restrict__ Wei,
    const float* __restrict__ bei, float* __restrict__ attn,
    float* __restrict__ deg, int* __restrict__ cnt, long long EH)
{
    const long long gid = (long long)blockIdx.x * blockDim.x + threadIdx.x;
    if (gid >= EH) return;
    const int e  = (int)(gid >> 2);
    const int hh = (int)(gid & 3);
    const int s = src[e], t = tgt[e];
    const float4* qp = (const float4*)(Q + (size_t)s * 128 + hh * 32);
    const float4* kp = (const float4*)(K + (size_t)t * 128 + hh * 32);
    float dot = 0.f;
#pragma unroll
    for (int i = 0; i < 8; ++i) {
        const float4 q = qp[i], k = kp[i];
        dot += q.x * k.x + q.y * k.y + q.z * k.z + q.w * k.w;
    }
    const float w = ew[e];
    float b = w * Wei[hh] + bei[hh];
    b = (b > 0.f) ? b : NEG_SLOPE * b;
    const float ex = __expf(dot * 0.17677669529663687f + b);  // 1/sqrt(32)
    attn[(size_t)e * 4 + hh] = ex;
    atomicAdd(deg + (size_t)t * 4 + hh, ex);
    if (hh == 0) atomicAdd(cnt + t, 1);
}

// ---------------------------------------------------------------------------
// CSR build: block-wise exclusive scan of per-node counts
// ---------------------------------------------------------------------------
__global__ __launch_bounds__(256) void scan1(const int* __restrict__ cnt,
                                             int* __restrict__ offs,
                                             int* __restrict__ bsums, int V)
{
    __shared__ int sh[256];
    const int t = threadIdx.x;
    const int base = blockIdx.x * 1024;
    int v[4];
    int s = 0;
#pragma unroll
    for (int i = 0; i < 4; ++i) {
        const int idx = base + t * 4 + i;
        v[i] = (idx < V) ? cnt[idx] : 0;
        s += v[i];
    }
    sh[t] = s;
    __syncthreads();
    for (int off = 1; off < 256; off <<= 1) {
        const int x = (t >= off) ? sh[t - off] : 0;
        __syncthreads();
        sh[t] += x;
        __syncthreads();
    }
    int run = (t > 0) ? sh[t - 1] : 0;
#pragma unroll
    for (int i = 0; i < 4; ++i) {
        const int idx = base + t * 4 + i;
        if (idx < V) offs[idx] = run;
        run += v[i];
    }
    if (t == 255) bsums[blockIdx.x] = sh[255];
}

__global__ void scan2(int* __restrict__ bsums, int nb)
{
    if (threadIdx.x == 0 && blockIdx.x == 0) {
        int run = 0;
        for (int i = 0; i < nb; ++i) { const int x = bsums[i]; bsums[i] = run; run += x; }
    }
}

__global__ __launch_bounds__(256) void scan3(int* __restrict__ offs,
                                             const int* __restrict__ bsums,
                                             int* __restrict__ fill, int V)
{
    const int v = blockIdx.x * blockDim.x + threadIdx.x;
    if (v >= V) return;
    const int o = offs[v] + bsums[v >> 10];
    offs[v] = o;
    fill[v] = o;
}

// ---------------------------------------------------------------------------
// Scatter edges into target-sorted order, materializing src + attn*ew coefs
// so the gather kernel has zero indirection.
// ---------------------------------------------------------------------------
__global__ __launch_bounds__(256) void scatter_edges(
    const int* __restrict__ src, const int* __restrict__ tgt,
    const float* __restrict__ attn, const float* __restrict__ ew,
    int* __restrict__ fill, int* __restrict__ srcs_s,
    float4* __restrict__ coef, int E)
{
    const int e = blockIdx.x * blockDim.x + threadIdx.x;
    if (e >= E) return;
    const int pos = atomicAdd(fill + tgt[e], 1);
    srcs_s[pos] = src[e];
    const float w = ew[e];
    const float4 a = *(const float4*)(attn + (size_t)e * 4);
    coef[pos] = make_float4(a.x * w, a.y * w, a.z * w, a.w * w);
}

// ---------------------------------------------------------------------------
// Per-node aggregation, one wave per node (64 lanes x float2 = 128 dims).
// Unrolled x4: all Vv row loads independent -> 4x memory-level parallelism.
// ---------------------------------------------------------------------------
__global__ __launch_bounds__(256) void gather_agg(
    const float* __restrict__ Vv, const int* __restrict__ srcs,
    const float* __restrict__ coef, const float* __restrict__ deg,
    const int* __restrict__ offs, const int* __restrict__ fill,
    float* __restrict__ accum, int V)
{
    const int node = blockIdx.x * 4 + (threadIdx.x >> 6);
    if (node >= V) return;
    const int l  = threadIdx.x & 63;
    const int hh = l >> 4;                       // dims l*2, l*2+1 share a head
    const float2* __restrict__ Vv2 = (const float2*)Vv;
    const int start = offs[node];
    const int end   = fill[node];
    const float inv = 1.0f / (deg[(size_t)node * 4 + hh] + 1e-16f);
    float ax = 0.f, ay = 0.f;
    int p = start;
#pragma unroll 1
    for (; p + 4 <= end; p += 4) {
        const int s0 = srcs[p + 0], s1 = srcs[p + 1];
        const int s2 = srcs[p + 2], s3 = srcs[p + 3];
        const float c0 = coef[(size_t)(p + 0) * 4 + hh];
        const float c1 = coef[(size_t)(p + 1) * 4 + hh];
        const float c2 = coef[(size_t)(p + 2) * 4 + hh];
        const float c3 = coef[(size_t)(p + 3) * 4 + hh];
        const float2 v0 = Vv2[(size_t)s0 * 64 + l];
        const float2 v1 = Vv2[(size_t)s1 * 64 + l];
        const float2 v2 = Vv2[(size_t)s2 * 64 + l];
        const float2 v3 = Vv2[(size_t)s3 * 64 + l];
        ax += c0 * v0.x; ay += c0 * v0.y;
        ax += c1 * v1.x; ay += c1 * v1.y;
        ax += c2 * v2.x; ay += c2 * v2.y;
        ax += c3 * v3.x; ay += c3 * v3.y;
    }
    for (; p < end; ++p) {
        const float c = coef[(size_t)p * 4 + hh];
        const float2 v = Vv2[(size_t)srcs[p] * 64 + l];
        ax += c * v.x; ay += c * v.y;
    }
    *(float2*)(accum + (size_t)node * 128 + l * 2) = make_float2(ax * inv, ay * inv);
}

// ---------------------------------------------------------------------------
extern "C" void kernel_launch(void* const* d_in, const int* in_sizes, int n_in,
                              void* d_out, int out_size, void* d_ws, size_t ws_size,
                              hipStream_t stream)
{
    const float* h   = (const float*)d_in[0];
    const int*   ei  = (const int*)  d_in[1];
    const float* ew  = (const float*)d_in[2];
    const float* Wq  = (const float*)d_in[3];
    const float* bq  = (const float*)d_in[4];
    const float* Wk  = (const float*)d_in[5];
    const float* bk  = (const float*)d_in[6];
    const float* Wv  = (const float*)d_in[7];
    const float* bv  = (const float*)d_in[8];
    const float* Wo  = (const float*)d_in[9];
    const float* bo  = (const float*)d_in[10];
    const float* Wei = (const float*)d_in[11];
    const float* bei = (const float*)d_in[12];

    const int V = in_sizes[0] / 128;
    const int E = in_sizes[2];
    const int* src = ei;
    const int* tgt = ei + E;

    // workspace layout
    float* Q     = (float*)d_ws;
    float* Km    = Q  + (size_t)V * 128;
    float* Vm    = Km + (size_t)V * 128;
    float* attn  = Vm + (size_t)V * 128;
    float* deg   = attn + (size_t)E * 4;
    float* accum = deg + (size_t)V * 4;
    float* coef  = accum + (size_t)V * 128;   // [E][4], target-sorted
    int*   srcs  = (int*)(coef + (size_t)E * 4);
    int*   cnt   = srcs + E;
    int*   offs  = cnt  + V;
    int*   fill  = offs + V + 1;
    int*   bsums = fill + V;

    hipMemsetAsync(deg, 0, (size_t)V * 4 * sizeof(float), stream);
    hipMemsetAsync(cnt, 0, (size_t)V * sizeof(int), stream);

    const int gemmGrid = (V + 63) / 64;
    gemm_qkv<<<gemmGrid, 256, 0, stream>>>(h, Wq, Wk, Wv, bq, bk, bv, Q, Km, Vm, V);

    const long long EH = (long long)E * 4;
    edge_logits<<<(int)((EH + 255) / 256), 256, 0, stream>>>(
        src, tgt, ew, Q, Km, Wei, bei, attn, deg, cnt, EH);

    const int nb = (V + 1023) / 1024;
    scan1<<<nb, 256, 0, stream>>>(cnt, offs, bsums, V);
    scan2<<<1, 64, 0, stream>>>(bsums, nb);
    scan3<<<(V + 255) / 256, 256, 0, stream>>>(offs, bsums, fill, V);
    scatter_edges<<<(E + 255) / 256, 256, 0, stream>>>(
        src, tgt, attn, ew, fill, srcs, (float4*)coef, E);

    gather_agg<<<(V + 3) / 4, 256, 0, stream>>>(
        Vm, srcs, coef, deg, offs, fill, accum, V);

    gemm128<<<gemmGrid, 256, 0, stream>>>(accum, Wo, bo, (float*)d_out, V, 1);
}

// Round 3
// 344.554 us; speedup vs baseline: 1.6458x; 1.1427x over previous
//
#include <hip/hip_runtime.h>
#include <hip/hip_bf16.h>

#define NEG_SLOPE 0.2f

// ---------------------------------------------------------------------------
// Tiled f32 GEMM: D[V,128] = act(A[V,128] @ W[128,128] + bias), optional lrelu
// ---------------------------------------------------------------------------
__global__ __launch_bounds__(256) void gemm128(const float* __restrict__ A,
                                               const float* __restrict__ W,
                                               const float* __restrict__ bias,
                                               float* __restrict__ D,
                                               int V, int lrelu)
{
    __shared__ float As[32][65];    // transposed [k][row], padded
    __shared__ float Bs[32][128];   // [k][col]
    const int tid = threadIdx.x;
    const int tx = tid & 15;
    const int ty = tid >> 4;
    const int row0 = blockIdx.x * 64;

    float acc[4][8];
#pragma unroll
    for (int i = 0; i < 4; ++i)
#pragma unroll
        for (int j = 0; j < 8; ++j) acc[i][j] = 0.f;

    for (int k0 = 0; k0 < 128; k0 += 32) {
        {
            const int c = (tid & 7) * 4;
#pragma unroll
            for (int p = 0; p < 2; ++p) {
                const int r = (tid >> 3) + 32 * p;
                const int gr = row0 + r;
                float4 a = make_float4(0.f, 0.f, 0.f, 0.f);
                if (gr < V) a = *(const float4*)(A + (size_t)gr * 128 + k0 + c);
                As[c + 0][r] = a.x; As[c + 1][r] = a.y;
                As[c + 2][r] = a.z; As[c + 3][r] = a.w;
            }
        }
        {
            const int r = tid >> 5;
            const int c = (tid & 31) * 4;
#pragma unroll
            for (int p = 0; p < 4; ++p) {
                float4 b = *(const float4*)(W + (size_t)(k0 + r + 8 * p) * 128 + c);
                *(float4*)&Bs[r + 8 * p][c] = b;
            }
        }
        __syncthreads();
#pragma unroll 8
        for (int kk = 0; kk < 32; ++kk) {
            float a[4];
#pragma unroll
            for (int i = 0; i < 4; ++i) a[i] = As[kk][ty * 4 + i];
            const float4 b0 = *(const float4*)&Bs[kk][tx * 8];
            const float4 b1 = *(const float4*)&Bs[kk][tx * 8 + 4];
            const float b[8] = {b0.x, b0.y, b0.z, b0.w, b1.x, b1.y, b1.z, b1.w};
#pragma unroll
            for (int i = 0; i < 4; ++i)
#pragma unroll
                for (int j = 0; j < 8; ++j) acc[i][j] += a[i] * b[j];
        }
        __syncthreads();
    }

#pragma unroll
    for (int i = 0; i < 4; ++i) {
        const int gr = row0 + ty * 4 + i;
        if (gr >= V) continue;
#pragma unroll
        for (int j = 0; j < 8; j += 4) {
            float4 o;
            float* op = &o.x;
#pragma unroll
            for (int jj = 0; jj < 4; ++jj) {
                const int c = tx * 8 + j + jj;
                float x = acc[i][j + jj] + bias[c];
                if (lrelu) x = (x > 0.f) ? x : NEG_SLOPE * x;
                op[jj] = x;
            }
            *(float4*)(D + (size_t)gr * 128 + tx * 8 + j) = o;
        }
    }
}

// ---------------------------------------------------------------------------
// Fused Q/K/V projection: three GEMMs sharing the A-tile staging.
// ---------------------------------------------------------------------------
__global__ __launch_bounds__(256) void gemm_qkv(
    const float* __restrict__ A,
    const float* __restrict__ W0, const float* __restrict__ W1, const float* __restrict__ W2,
    const float* __restrict__ b0, const float* __restrict__ b1, const float* __restrict__ b2,
    float* __restrict__ D0, float* __restrict__ D1, float* __restrict__ D2, int V)
{
    __shared__ float As[32][65];
    __shared__ float Bs[3][32][128];
    const int tid = threadIdx.x;
    const int tx = tid & 15;
    const int ty = tid >> 4;
    const int row0 = blockIdx.x * 64;
    const float* Ws[3] = {W0, W1, W2};
    const float* bs[3] = {b0, b1, b2};
    float* Ds[3] = {D0, D1, D2};

    float acc[3][4][8];
#pragma unroll
    for (int m = 0; m < 3; ++m)
#pragma unroll
        for (int i = 0; i < 4; ++i)
#pragma unroll
            for (int j = 0; j < 8; ++j) acc[m][i][j] = 0.f;

    for (int k0 = 0; k0 < 128; k0 += 32) {
        {
            const int c = (tid & 7) * 4;
#pragma unroll
            for (int p = 0; p < 2; ++p) {
                const int r = (tid >> 3) + 32 * p;
                const int gr = row0 + r;
                float4 a = make_float4(0.f, 0.f, 0.f, 0.f);
                if (gr < V) a = *(const float4*)(A + (size_t)gr * 128 + k0 + c);
                As[c + 0][r] = a.x; As[c + 1][r] = a.y;
                As[c + 2][r] = a.z; As[c + 3][r] = a.w;
            }
        }
        {
            const int r = tid >> 5;
            const int c = (tid & 31) * 4;
#pragma unroll
            for (int m = 0; m < 3; ++m)
#pragma unroll
                for (int p = 0; p < 4; ++p) {
                    float4 b = *(const float4*)(Ws[m] + (size_t)(k0 + r + 8 * p) * 128 + c);
                    *(float4*)&Bs[m][r + 8 * p][c] = b;
                }
        }
        __syncthreads();
#pragma unroll 4
        for (int kk = 0; kk < 32; ++kk) {
            float a[4];
#pragma unroll
            for (int i = 0; i < 4; ++i) a[i] = As[kk][ty * 4 + i];
#pragma unroll
            for (int m = 0; m < 3; ++m) {
                const float4 q0 = *(const float4*)&Bs[m][kk][tx * 8];
                const float4 q1 = *(const float4*)&Bs[m][kk][tx * 8 + 4];
                const float b[8] = {q0.x, q0.y, q0.z, q0.w, q1.x, q1.y, q1.z, q1.w};
#pragma unroll
                for (int i = 0; i < 4; ++i)
#pragma unroll
                    for (int j = 0; j < 8; ++j) acc[m][i][j] += a[i] * b[j];
            }
        }
        __syncthreads();
    }

#pragma unroll
    for (int m = 0; m < 3; ++m)
#pragma unroll
        for (int i = 0; i < 4; ++i) {
            const int gr = row0 + ty * 4 + i;
            if (gr >= V) continue;
#pragma unroll
            for (int j = 0; j < 8; j += 4) {
                float4 o;
                float* op = &o.x;
#pragma unroll
                for (int jj = 0; jj < 4; ++jj)
                    op[jj] = acc[m][i][j + jj] + bs[m][tx * 8 + j + jj];
                *(float4*)(Ds[m] + (size_t)gr * 128 + tx * 8 + j) = o;
            }
        }
}

// ---------------------------------------------------------------------------
// Per-target in-degree count
// ---------------------------------------------------------------------------
__global__ __launch_bounds__(256) void count_tgt(const int* __restrict__ tgt,
                                                 int* __restrict__ cnt, int E)
{
    const int e = blockIdx.x * blockDim.x + threadIdx.x;
    if (e < E) atomicAdd(cnt + tgt[e], 1);
}

// ---------------------------------------------------------------------------
// CSR build: block-wise exclusive scan of per-node counts
// ---------------------------------------------------------------------------
__global__ __launch_bounds__(256) void scan1(const int* __restrict__ cnt,
                                             int* __restrict__ offs,
                                             int* __restrict__ bsums, int V)
{
    __shared__ int sh[256];
    const int t = threadIdx.x;
    const int base = blockIdx.x * 1024;
    int v[4];
    int s = 0;
#pragma unroll
    for (int i = 0; i < 4; ++i) {
        const int idx = base + t * 4 + i;
        v[i] = (idx < V) ? cnt[idx] : 0;
        s += v[i];
    }
    sh[t] = s;
    __syncthreads();
    for (int off = 1; off < 256; off <<= 1) {
        const int x = (t >= off) ? sh[t - off] : 0;
        __syncthreads();
        sh[t] += x;
        __syncthreads();
    }
    int run = (t > 0) ? sh[t - 1] : 0;
#pragma unroll
    for (int i = 0; i < 4; ++i) {
        const int idx = base + t * 4 + i;
        if (idx < V) offs[idx] = run;
        run += v[i];
    }
    if (t == 255) bsums[blockIdx.x] = sh[255];
}

__global__ void scan2(int* __restrict__ bsums, int nb)
{
    if (threadIdx.x == 0 && blockIdx.x == 0) {
        int run = 0;
        for (int i = 0; i < nb; ++i) { const int x = bsums[i]; bsums[i] = run; run += x; }
    }
}

__global__ __launch_bounds__(256) void scan3(int* __restrict__ offs,
                                             const int* __restrict__ bsums,
                                             int* __restrict__ fill, int V)
{
    const int v = blockIdx.x * blockDim.x + threadIdx.x;
    if (v >= V) return;
    const int o = offs[v] + bsums[v >> 10];
    offs[v] = o;
    fill[v] = o;
}

// ---------------------------------------------------------------------------
// Scatter edges into target-sorted order: src id + edge weight.
// ---------------------------------------------------------------------------
__global__ __launch_bounds__(256) void scatter_edges(
    const int* __restrict__ src, const int* __restrict__ tgt,
    const float* __restrict__ ew, int* __restrict__ fill,
    int* __restrict__ srcs_s, float* __restrict__ ew_s, int E)
{
    const int e = blockIdx.x * blockDim.x + threadIdx.x;
    if (e >= E) return;
    const int pos = atomicAdd(fill + tgt[e], 1);
    srcs_s[pos] = src[e];
    ew_s[pos]   = ew[e];
}

// ---------------------------------------------------------------------------
// Fused per-node kernel: QK^T logits + exp + softmax-denominator + weighted
// Vv aggregation + normalization. One wave per node.
//   Stage A: lane = j*4+h computes dot(Q[src_j] head h, K[node] head h),
//            p = exp(dot/sqrt(32) + lrelu(w*We[h]+be[h])), coef = p*w.
//   Stage B: lane owns dims {2l, 2l+1} (head l>>4); coefs broadcast by shfl;
//            Vv row loads coalesced, 16 independent rows in flight.
//   out[node] = (sum_e coef_e * Vv[src_e]) / (sum_e p_e + 1e-16)  per head.
// No atomics, K row loaded once per node.
// ---------------------------------------------------------------------------
__global__ __launch_bounds__(256) void fused_agg(
    const float* __restrict__ Q, const float* __restrict__ K,
    const float* __restrict__ Vv, const int* __restrict__ srcs,
    const float* __restrict__ ews, const int* __restrict__ offs,
    const int* __restrict__ fill, const float* __restrict__ Wei,
    const float* __restrict__ bei, float* __restrict__ accum, int V)
{
    __shared__ float Ksh[4][128];
    const int wid  = threadIdx.x >> 6;
    const int node = blockIdx.x * 4 + wid;
    if (node >= V) return;
    const int l  = threadIdx.x & 63;
    const int h  = l & 3;    // stage-A head
    const int hd = l >> 4;   // stage-B head

    // stage K row into LDS (wave-local; no cross-wave sharing -> no barrier)
    *(float2*)&Ksh[wid][l * 2] = *(const float2*)(K + (size_t)node * 128 + l * 2);

    const float weH = Wei[h], beH = bei[h];
    const int start = offs[node];
    const int end   = fill[node];
    const float2* __restrict__ Vv2 = (const float2*)Vv;

    float degacc = 0.f;
    float ax = 0.f, ay = 0.f;

    for (int b0 = start; b0 < end; b0 += 16) {
        const int nj = min(16, end - b0);
        const int jj = l >> 2;
        int   s = 0;
        float w = 0.f, p = 0.f;
        if (jj < nj) {
            const int eidx = b0 + jj;
            s = srcs[eidx];
            w = ews[eidx];
            const float4* qp = (const float4*)(Q + (size_t)s * 128 + h * 32);
            float dot = 0.f;
#pragma unroll
            for (int i = 0; i < 8; ++i) {
                const float4 q = qp[i];
                const float4 k = *(const float4*)&Ksh[wid][h * 32 + i * 4];
                dot += q.x * k.x + q.y * k.y + q.z * k.z + q.w * k.w;
            }
            float bb = w * weH + beH;
            bb = (bb > 0.f) ? bb : NEG_SLOPE * bb;
            p = __expf(dot * 0.17677669529663687f + bb);
        }
        degacc += p;
        const float coef = p * w;

        if (nj == 16) {
#pragma unroll
            for (int j = 0; j < 16; ++j) {
                const float cj = __shfl(coef, j * 4 + hd);
                const int   sj = __shfl(s,    j * 4);
                const float2 v = Vv2[(size_t)sj * 64 + l];
                ax += cj * v.x; ay += cj * v.y;
            }
        } else {
            for (int j = 0; j < nj; ++j) {
                const float cj = __shfl(coef, j * 4 + hd);
                const int   sj = __shfl(s,    j * 4);
                const float2 v = Vv2[(size_t)sj * 64 + l];
                ax += cj * v.x; ay += cj * v.y;
            }
        }
    }

    // reduce degacc across the 16 lanes sharing (l&3) -> deg[l&3] in every lane
    float d = degacc;
    d += __shfl_xor(d, 4);
    d += __shfl_xor(d, 8);
    d += __shfl_xor(d, 16);
    d += __shfl_xor(d, 32);
    const float deg = __shfl(d, hd);      // lane 'hd' holds head hd's sum
    const float inv = 1.0f / (deg + 1e-16f);

    *(float2*)(accum + (size_t)node * 128 + l * 2) = make_float2(ax * inv, ay * inv);
}

// ---------------------------------------------------------------------------
extern "C" void kernel_launch(void* const* d_in, const int* in_sizes, int n_in,
                              void* d_out, int out_size, void* d_ws, size_t ws_size,
                              hipStream_t stream)
{
    const float* h   = (const float*)d_in[0];
    const int*   ei  = (const int*)  d_in[1];
    const float* ew  = (const float*)d_in[2];
    const float* Wq  = (const float*)d_in[3];
    const float* bq  = (const float*)d_in[4];
    const float* Wk  = (const float*)d_in[5];
    const float* bk  = (const float*)d_in[6];
    const float* Wv  = (const float*)d_in[7];
    const float* bv  = (const float*)d_in[8];
    const float* Wo  = (const float*)d_in[9];
    const float* bo  = (const float*)d_in[10];
    const float* Wei = (const float*)d_in[11];
    const float* bei = (const float*)d_in[12];

    const int V = in_sizes[0] / 128;
    const int E = in_sizes[2];
    const int* src = ei;
    const int* tgt = ei + E;

    // workspace layout
    float* Q     = (float*)d_ws;
    float* Km    = Q  + (size_t)V * 128;
    float* Vm    = Km + (size_t)V * 128;
    float* accum = Vm + (size_t)V * 128;
    float* ew_s  = accum + (size_t)V * 128;
    int*   srcs  = (int*)(ew_s + E);
    int*   cnt   = srcs + E;
    int*   offs  = cnt  + V;
    int*   fill  = offs + V + 1;
    int*   bsums = fill + V;

    hipMemsetAsync(cnt, 0, (size_t)V * sizeof(int), stream);

    const int gemmGrid = (V + 63) / 64;
    gemm_qkv<<<gemmGrid, 256, 0, stream>>>(h, Wq, Wk, Wv, bq, bk, bv, Q, Km, Vm, V);

    count_tgt<<<(E + 255) / 256, 256, 0, stream>>>(tgt, cnt, E);
    const int nb = (V + 1023) / 1024;
    scan1<<<nb, 256, 0, stream>>>(cnt, offs, bsums, V);
    scan2<<<1, 64, 0, stream>>>(bsums, nb);
    scan3<<<(V + 255) / 256, 256, 0, stream>>>(offs, bsums, fill, V);
    scatter_edges<<<(E + 255) / 256, 256, 0, stream>>>(
        src, tgt, ew, fill, srcs, ew_s, E);

    fused_agg<<<(V + 3) / 4, 256, 0, stream>>>(
        Q, Km, Vm, srcs, ew_s, offs, fill, Wei, bei, accum, V);

    gemm128<<<gemmGrid, 256, 0, stream>>>(accum, Wo, bo, (float*)d_out, V, 1);
}

// Round 4
// 339.918 us; speedup vs baseline: 1.6683x; 1.0136x over previous
//
#include <hip/hip_runtime.h>
#include <hip/hip_bf16.h>

#define NEG_SLOPE 0.2f

// ---------------------------------------------------------------------------
// Tiled f32 GEMM: D[V,128] = act(A[V,128] @ W[128,128] + bias), optional lrelu
// ---------------------------------------------------------------------------
__global__ __launch_bounds__(256) void gemm128(const float* __restrict__ A,
                                               const float* __restrict__ W,
                                               const float* __restrict__ bias,
                                               float* __restrict__ D,
                                               int V, int lrelu)
{
    __shared__ float As[32][65];    // transposed [k][row], padded
    __shared__ float Bs[32][128];   // [k][col]
    const int tid = threadIdx.x;
    const int tx = tid & 15;
    const int ty = tid >> 4;
    const int row0 = blockIdx.x * 64;

    float acc[4][8];
#pragma unroll
    for (int i = 0; i < 4; ++i)
#pragma unroll
        for (int j = 0; j < 8; ++j) acc[i][j] = 0.f;

    for (int k0 = 0; k0 < 128; k0 += 32) {
        {
            const int c = (tid & 7) * 4;
#pragma unroll
            for (int p = 0; p < 2; ++p) {
                const int r = (tid >> 3) + 32 * p;
                const int gr = row0 + r;
                float4 a = make_float4(0.f, 0.f, 0.f, 0.f);
                if (gr < V) a = *(const float4*)(A + (size_t)gr * 128 + k0 + c);
                As[c + 0][r] = a.x; As[c + 1][r] = a.y;
                As[c + 2][r] = a.z; As[c + 3][r] = a.w;
            }
        }
        {
            const int r = tid >> 5;
            const int c = (tid & 31) * 4;
#pragma unroll
            for (int p = 0; p < 4; ++p) {
                float4 b = *(const float4*)(W + (size_t)(k0 + r + 8 * p) * 128 + c);
                *(float4*)&Bs[r + 8 * p][c] = b;
            }
        }
        __syncthreads();
#pragma unroll 8
        for (int kk = 0; kk < 32; ++kk) {
            float a[4];
#pragma unroll
            for (int i = 0; i < 4; ++i) a[i] = As[kk][ty * 4 + i];
            const float4 b0 = *(const float4*)&Bs[kk][tx * 8];
            const float4 b1 = *(const float4*)&Bs[kk][tx * 8 + 4];
            const float b[8] = {b0.x, b0.y, b0.z, b0.w, b1.x, b1.y, b1.z, b1.w};
#pragma unroll
            for (int i = 0; i < 4; ++i)
#pragma unroll
                for (int j = 0; j < 8; ++j) acc[i][j] += a[i] * b[j];
        }
        __syncthreads();
    }

#pragma unroll
    for (int i = 0; i < 4; ++i) {
        const int gr = row0 + ty * 4 + i;
        if (gr >= V) continue;
#pragma unroll
        for (int j = 0; j < 8; j += 4) {
            float4 o;
            float* op = &o.x;
#pragma unroll
            for (int jj = 0; jj < 4; ++jj) {
                const int c = tx * 8 + j + jj;
                float x = acc[i][j + jj] + bias[c];
                if (lrelu) x = (x > 0.f) ? x : NEG_SLOPE * x;
                op[jj] = x;
            }
            *(float4*)(D + (size_t)gr * 128 + tx * 8 + j) = o;
        }
    }
}

// ---------------------------------------------------------------------------
// Fused Q/K/V projection: three GEMMs sharing the A-tile staging.
// ---------------------------------------------------------------------------
__global__ __launch_bounds__(256) void gemm_qkv(
    const float* __restrict__ A,
    const float* __restrict__ W0, const float* __restrict__ W1, const float* __restrict__ W2,
    const float* __restrict__ b0, const float* __restrict__ b1, const float* __restrict__ b2,
    float* __restrict__ D0, float* __restrict__ D1, float* __restrict__ D2, int V)
{
    __shared__ float As[32][65];
    __shared__ float Bs[3][32][128];
    const int tid = threadIdx.x;
    const int tx = tid & 15;
    const int ty = tid >> 4;
    const int row0 = blockIdx.x * 64;
    const float* Ws[3] = {W0, W1, W2};
    const float* bs[3] = {b0, b1, b2};
    float* Ds[3] = {D0, D1, D2};

    float acc[3][4][8];
#pragma unroll
    for (int m = 0; m < 3; ++m)
#pragma unroll
        for (int i = 0; i < 4; ++i)
#pragma unroll
            for (int j = 0; j < 8; ++j) acc[m][i][j] = 0.f;

    for (int k0 = 0; k0 < 128; k0 += 32) {
        {
            const int c = (tid & 7) * 4;
#pragma unroll
            for (int p = 0; p < 2; ++p) {
                const int r = (tid >> 3) + 32 * p;
                const int gr = row0 + r;
                float4 a = make_float4(0.f, 0.f, 0.f, 0.f);
                if (gr < V) a = *(const float4*)(A + (size_t)gr * 128 + k0 + c);
                As[c + 0][r] = a.x; As[c + 1][r] = a.y;
                As[c + 2][r] = a.z; As[c + 3][r] = a.w;
            }
        }
        {
            const int r = tid >> 5;
            const int c = (tid & 31) * 4;
#pragma unroll
            for (int m = 0; m < 3; ++m)
#pragma unroll
                for (int p = 0; p < 4; ++p) {
                    float4 b = *(const float4*)(Ws[m] + (size_t)(k0 + r + 8 * p) * 128 + c);
                    *(float4*)&Bs[m][r + 8 * p][c] = b;
                }
        }
        __syncthreads();
#pragma unroll 4
        for (int kk = 0; kk < 32; ++kk) {
            float a[4];
#pragma unroll
            for (int i = 0; i < 4; ++i) a[i] = As[kk][ty * 4 + i];
#pragma unroll
            for (int m = 0; m < 3; ++m) {
                const float4 q0 = *(const float4*)&Bs[m][kk][tx * 8];
                const float4 q1 = *(const float4*)&Bs[m][kk][tx * 8 + 4];
                const float b[8] = {q0.x, q0.y, q0.z, q0.w, q1.x, q1.y, q1.z, q1.w};
#pragma unroll
                for (int i = 0; i < 4; ++i)
#pragma unroll
                    for (int j = 0; j < 8; ++j) acc[m][i][j] += a[i] * b[j];
            }
        }
        __syncthreads();
    }

#pragma unroll
    for (int m = 0; m < 3; ++m)
#pragma unroll
        for (int i = 0; i < 4; ++i) {
            const int gr = row0 + ty * 4 + i;
            if (gr >= V) continue;
#pragma unroll
            for (int j = 0; j < 8; j += 4) {
                float4 o;
                float* op = &o.x;
#pragma unroll
                for (int jj = 0; jj < 4; ++jj)
                    op[jj] = acc[m][i][j + jj] + bs[m][tx * 8 + j + jj];
                *(float4*)(Ds[m] + (size_t)gr * 128 + tx * 8 + j) = o;
            }
        }
}

// ---------------------------------------------------------------------------
// Per-target in-degree count
// ---------------------------------------------------------------------------
__global__ __launch_bounds__(256) void count_tgt(const int* __restrict__ tgt,
                                                 int* __restrict__ cnt, int E)
{
    const int e = blockIdx.x * blockDim.x + threadIdx.x;
    if (e < E) atomicAdd(cnt + tgt[e], 1);
}

// ---------------------------------------------------------------------------
// CSR build: block-wise exclusive scan of per-node counts
// ---------------------------------------------------------------------------
__global__ __launch_bounds__(256) void scan1(const int* __restrict__ cnt,
                                             int* __restrict__ offs,
                                             int* __restrict__ bsums, int V)
{
    __shared__ int sh[256];
    const int t = threadIdx.x;
    const int base = blockIdx.x * 1024;
    int v[4];
    int s = 0;
#pragma unroll
    for (int i = 0; i < 4; ++i) {
        const int idx = base + t * 4 + i;
        v[i] = (idx < V) ? cnt[idx] : 0;
        s += v[i];
    }
    sh[t] = s;
    __syncthreads();
    for (int off = 1; off < 256; off <<= 1) {
        const int x = (t >= off) ? sh[t - off] : 0;
        __syncthreads();
        sh[t] += x;
        __syncthreads();
    }
    int run = (t > 0) ? sh[t - 1] : 0;
#pragma unroll
    for (int i = 0; i < 4; ++i) {
        const int idx = base + t * 4 + i;
        if (idx < V) offs[idx] = run;
        run += v[i];
    }
    if (t == 255) bsums[blockIdx.x] = sh[255];
}

__global__ void scan2(int* __restrict__ bsums, int nb)
{
    if (threadIdx.x == 0 && blockIdx.x == 0) {
        int run = 0;
        for (int i = 0; i < nb; ++i) { const int x = bsums[i]; bsums[i] = run; run += x; }
    }
}

__global__ __launch_bounds__(256) void scan3(int* __restrict__ offs,
                                             const int* __restrict__ bsums,
                                             int* __restrict__ fill, int V)
{
    const int v = blockIdx.x * blockDim.x + threadIdx.x;
    if (v >= V) return;
    const int o = offs[v] + bsums[v >> 10];
    offs[v] = o;
    fill[v] = o;
}

// ---------------------------------------------------------------------------
// Scatter edges into target-sorted order: src id + edge weight.
// ---------------------------------------------------------------------------
__global__ __launch_bounds__(256) void scatter_edges(
    const int* __restrict__ src, const int* __restrict__ tgt,
    const float* __restrict__ ew, int* __restrict__ fill,
    int* __restrict__ srcs_s, float* __restrict__ ew_s, int E)
{
    const int e = blockIdx.x * blockDim.x + threadIdx.x;
    if (e >= E) return;
    const int pos = atomicAdd(fill + tgt[e], 1);
    srcs_s[pos] = src[e];
    ew_s[pos]   = ew[e];
}

// ---------------------------------------------------------------------------
// Fused per-node kernel: QK^T logits + exp + softmax-denominator + weighted
// Vv aggregation + normalization. One wave per node.
//   Stage A: lane = j*4+h computes dot(Q[src_j] head h, K[node] head h),
//            p = exp(dot/sqrt(32) + lrelu(w*We[h]+be[h])), coef = p*w.
//   Stage B: lane owns dims {2l, 2l+1} (head l>>4); coefs broadcast by shfl;
//            Vv row loads coalesced, 16 independent rows in flight.
//   out[node] = (sum_e coef_e * Vv[src_e]) / (sum_e p_e + 1e-16)  per head.
// No atomics, K row loaded once per node.
// ---------------------------------------------------------------------------
__global__ __launch_bounds__(256) void fused_agg(
    const float* __restrict__ Q, const float* __restrict__ K,
    const float* __restrict__ Vv, const int* __restrict__ srcs,
    const float* __restrict__ ews, const int* __restrict__ offs,
    const int* __restrict__ fill, const float* __restrict__ Wei,
    const float* __restrict__ bei, float* __restrict__ accum, int V)
{
    __shared__ float Ksh[4][128];
    const int wid  = threadIdx.x >> 6;
    const int node = blockIdx.x * 4 + wid;
    if (node >= V) return;
    const int l  = threadIdx.x & 63;
    const int h  = l & 3;    // stage-A head
    const int hd = l >> 4;   // stage-B head

    // stage K row into LDS (wave-local; no cross-wave sharing -> no barrier)
    *(float2*)&Ksh[wid][l * 2] = *(const float2*)(K + (size_t)node * 128 + l * 2);

    const float weH = Wei[h], beH = bei[h];
    const int start = offs[node];
    const int end   = fill[node];
    const float2* __restrict__ Vv2 = (const float2*)Vv;

    float degacc = 0.f;
    float ax = 0.f, ay = 0.f;

    for (int b0 = start; b0 < end; b0 += 16) {
        const int nj = min(16, end - b0);
        const int jj = l >> 2;
        int   s = 0;
        float w = 0.f, p = 0.f;
        if (jj < nj) {
            const int eidx = b0 + jj;
            s = srcs[eidx];
            w = ews[eidx];
            const float4* qp = (const float4*)(Q + (size_t)s * 128 + h * 32);
            float dot = 0.f;
#pragma unroll
            for (int i = 0; i < 8; ++i) {
                const float4 q = qp[i];
                const float4 k = *(const float4*)&Ksh[wid][h * 32 + i * 4];
                dot += q.x * k.x + q.y * k.y + q.z * k.z + q.w * k.w;
            }
            float bb = w * weH + beH;
            bb = (bb > 0.f) ? bb : NEG_SLOPE * bb;
            p = __expf(dot * 0.17677669529663687f + bb);
        }
        degacc += p;
        const float coef = p * w;

        if (nj == 16) {
#pragma unroll
            for (int j = 0; j < 16; ++j) {
                const float cj = __shfl(coef, j * 4 + hd);
                const int   sj = __shfl(s,    j * 4);
                const float2 v = Vv2[(size_t)sj * 64 + l];
                ax += cj * v.x; ay += cj * v.y;
            }
        } else {
            for (int j = 0; j < nj; ++j) {
                const float cj = __shfl(coef, j * 4 + hd);
                const int   sj = __shfl(s,    j * 4);
                const float2 v = Vv2[(size_t)sj * 64 + l];
                ax += cj * v.x; ay += cj * v.y;
            }
        }
    }

    // reduce degacc across the 16 lanes sharing (l&3) -> deg[l&3] in every lane
    float d = degacc;
    d += __shfl_xor(d, 4);
    d += __shfl_xor(d, 8);
    d += __shfl_xor(d, 16);
    d += __shfl_xor(d, 32);
    const float deg = __shfl(d, hd);      // lane 'hd' holds head hd's sum
    const float inv = 1.0f / (deg + 1e-16f);

    *(float2*)(accum + (size_t)node * 128 + l * 2) = make_float2(ax * inv, ay * inv);
}

// ---------------------------------------------------------------------------
extern "C" void kernel_launch(void* const* d_in, const int* in_sizes, int n_in,
                              void* d_out, int out_size, void* d_ws, size_t ws_size,
                              hipStream_t stream)
{
    const float* h   = (const float*)d_in[0];
    const int*   ei  = (const int*)  d_in[1];
    const float* ew  = (const float*)d_in[2];
    const float* Wq  = (const float*)d_in[3];
    const float* bq  = (const float*)d_in[4];
    const float* Wk  = (const float*)d_in[5];
    const float* bk  = (const float*)d_in[6];
    const float* Wv  = (const float*)d_in[7];
    const float* bv  = (const float*)d_in[8];
    const float* Wo  = (const float*)d_in[9];
    const float* bo  = (const float*)d_in[10];
    const float* Wei = (const float*)d_in[11];
    const float* bei = (const float*)d_in[12];

    const int V = in_sizes[0] / 128;
    const int E = in_sizes[2];
    const int* src = ei;
    const int* tgt = ei + E;

    // workspace layout
    float* Q     = (float*)d_ws;
    float* Km    = Q  + (size_t)V * 128;
    float* Vm    = Km + (size_t)V * 128;
    float* accum = Vm + (size_t)V * 128;
    float* ew_s  = accum + (size_t)V * 128;
    int*   srcs  = (int*)(ew_s + E);
    int*   cnt   = srcs + E;
    int*   offs  = cnt  + V;
    int*   fill  = offs + V + 1;
    int*   bsums = fill + V;

    hipMemsetAsync(cnt, 0, (size_t)V * sizeof(int), stream);

    const int gemmGrid = (V + 63) / 64;
    gemm_qkv<<<gemmGrid, 256, 0, stream>>>(h, Wq, Wk, Wv, bq, bk, bv, Q, Km, Vm, V);

    count_tgt<<<(E + 255) / 256, 256, 0, stream>>>(tgt, cnt, E);
    const int nb = (V + 1023) / 1024;
    scan1<<<nb, 256, 0, stream>>>(cnt, offs, bsums, V);
    scan2<<<1, 64, 0, stream>>>(bsums, nb);
    scan3<<<(V + 255) / 256, 256, 0, stream>>>(offs, bsums, fill, V);
    scatter_edges<<<(E + 255) / 256, 256, 0, stream>>>(
        src, tgt, ew, fill, srcs, ew_s, E);

    fused_agg<<<(V + 3) / 4, 256, 0, stream>>>(
        Q, Km, Vm, srcs, ew_s, offs, fill, Wei, bei, accum, V);

    gemm128<<<gemmGrid, 256, 0, stream>>>(accum, Wo, bo, (float*)d_out, V, 1);
}